// Round 1
// baseline (772.666 us; speedup 1.0000x reference)
//
#include <hip/hip_runtime.h>
#include <math.h>

#define BATCH 8
#define CCH 384
#define NPIX 4096
#define NHEADS 6
#define SZ ((size_t)BATCH * CCH * NPIX) // 12,582,912 floats per (B,C,N) buffer

__device__ __forceinline__ float elu1(float x) { return x > 0.f ? x + 1.f : expf(x); }

// ---------------------------------------------------------------------------
// GEMM: out[b, m, n] = W[m, :] @ X[b, :, n] + bias[m]
// MODE 0: fused QKV (grid.y = 9 -> M=1152 stacked q,k,v) with rope+elu epilogue.
//         Rows of q/k tiles are PERMUTED so rope pairs (c, c+96) are adjacent:
//         local row r (even) -> u=r>>1, channel c_u = (u<96 ? u : u+96),
//         row r holds channel c_u, row r+1 holds channel c_u+96.
// MODE 1: FC (grid.y = 3), plain bias epilogue.
// Tiles: 128x128, BK=32, 256 threads, 8x8 micro-tile (2x2 clusters of 4x4).
// ---------------------------------------------------------------------------
template <int MODE>
__global__ __launch_bounds__(256) void gemm_kernel(
    const float* __restrict__ Xin,
    const float* __restrict__ Wa, const float* __restrict__ ba,
    const float* __restrict__ Wb, const float* __restrict__ bbv,
    const float* __restrict__ Wc, const float* __restrict__ bc,
    float* __restrict__ Oa, float* __restrict__ Ob, float* __restrict__ Oc)
{
    __shared__ float As[32][132]; // [k][m], padded
    __shared__ float Bs[32][132]; // [k][n], padded

    const int tid = threadIdx.x;
    const int n0 = blockIdx.x * 128;
    const int m0 = blockIdx.y * 128;
    const int bb = blockIdx.z;

    int which, r0;
    const float *Wsel, *bsel;
    float* osel;
    if (MODE == 0) {
        which = m0 / 384;
        r0 = m0 - which * 384;
        Wsel = (which == 0) ? Wa : (which == 1) ? Wb : Wc;
        bsel = (which == 0) ? ba : (which == 1) ? bbv : bc;
        osel = (which == 0) ? Oa : (which == 1) ? Ob : Oc;
    } else {
        which = 3; r0 = m0; Wsel = Wa; bsel = ba; osel = Oa;
    }

    // A loader: one row per thread, 16 consecutive k
    const int rowA = tid >> 1;
    const int kA = (tid & 1) * 16;
    const int r384A = r0 + rowA;
    int chA;
    if (MODE == 0 && which < 2) {
        int u = r384A >> 1;
        int cu = (u < 96) ? u : u + 96;
        chA = cu + 96 * (r384A & 1);
    } else {
        chA = r384A;
    }
    const float* wrow = Wsel + (size_t)chA * CCH;

    // B loader: one k-row per thread, 16 consecutive n
    const int kB = tid >> 3;
    const int colB = (tid & 7) * 16;
    const float* xbase = Xin + ((size_t)bb * CCH) * NPIX + n0 + colB;

    const int tx = tid & 15;
    const int ty = tid >> 4;

    float acc[2][2][4][4];
#pragma unroll
    for (int a = 0; a < 2; ++a)
#pragma unroll
        for (int b2 = 0; b2 < 2; ++b2)
#pragma unroll
            for (int i = 0; i < 4; ++i)
#pragma unroll
                for (int j = 0; j < 4; ++j) acc[a][b2][i][j] = 0.f;

    for (int k0 = 0; k0 < CCH; k0 += 32) {
        __syncthreads();
        {
            float4 a0 = *(const float4*)&wrow[k0 + kA + 0];
            float4 a1 = *(const float4*)&wrow[k0 + kA + 4];
            float4 a2 = *(const float4*)&wrow[k0 + kA + 8];
            float4 a3 = *(const float4*)&wrow[k0 + kA + 12];
            As[kA + 0][rowA] = a0.x;  As[kA + 1][rowA] = a0.y;
            As[kA + 2][rowA] = a0.z;  As[kA + 3][rowA] = a0.w;
            As[kA + 4][rowA] = a1.x;  As[kA + 5][rowA] = a1.y;
            As[kA + 6][rowA] = a1.z;  As[kA + 7][rowA] = a1.w;
            As[kA + 8][rowA] = a2.x;  As[kA + 9][rowA] = a2.y;
            As[kA + 10][rowA] = a2.z; As[kA + 11][rowA] = a2.w;
            As[kA + 12][rowA] = a3.x; As[kA + 13][rowA] = a3.y;
            As[kA + 14][rowA] = a3.z; As[kA + 15][rowA] = a3.w;

            const float* xr = xbase + (size_t)(k0 + kB) * NPIX;
            float4 b0 = *(const float4*)&xr[0];
            float4 b1 = *(const float4*)&xr[4];
            float4 b2 = *(const float4*)&xr[8];
            float4 b3 = *(const float4*)&xr[12];
            *(float4*)&Bs[kB][colB + 0] = b0;
            *(float4*)&Bs[kB][colB + 4] = b1;
            *(float4*)&Bs[kB][colB + 8] = b2;
            *(float4*)&Bs[kB][colB + 12] = b3;
        }
        __syncthreads();
#pragma unroll 8
        for (int kk = 0; kk < 32; ++kk) {
            float4 a0 = *(const float4*)&As[kk][ty * 4];
            float4 a1 = *(const float4*)&As[kk][64 + ty * 4];
            float4 q0 = *(const float4*)&Bs[kk][tx * 4];
            float4 q1 = *(const float4*)&Bs[kk][64 + tx * 4];
            float av[2][4] = {{a0.x, a0.y, a0.z, a0.w}, {a1.x, a1.y, a1.z, a1.w}};
            float bv2[2][4] = {{q0.x, q0.y, q0.z, q0.w}, {q1.x, q1.y, q1.z, q1.w}};
#pragma unroll
            for (int ci = 0; ci < 2; ++ci)
#pragma unroll
                for (int ii = 0; ii < 4; ++ii)
#pragma unroll
                    for (int cj = 0; cj < 2; ++cj)
#pragma unroll
                        for (int jj = 0; jj < 4; ++jj)
                            acc[ci][cj][ii][jj] += av[ci][ii] * bv2[cj][jj];
        }
    }

    const float KC = 0.13841367062030680f; // log2(10000)/96

    if (MODE == 1 || which == 2) {
        // plain epilogue: + bias
#pragma unroll
        for (int ci = 0; ci < 2; ++ci)
#pragma unroll
            for (int ii = 0; ii < 4; ++ii) {
                int r384 = r0 + ci * 64 + ty * 4 + ii;
                float bias = bsel[r384];
                float* orow = osel + ((size_t)bb * CCH + r384) * NPIX + n0;
#pragma unroll
                for (int cj = 0; cj < 2; ++cj) {
                    float4 o4;
                    o4.x = acc[ci][cj][ii][0] + bias;
                    o4.y = acc[ci][cj][ii][1] + bias;
                    o4.z = acc[ci][cj][ii][2] + bias;
                    o4.w = acc[ci][cj][ii][3] + bias;
                    *(float4*)&orow[cj * 64 + tx * 4] = o4;
                }
            }
    } else {
        // rope + elu epilogue (q: which==0, k: which==1)
        const float qscale = 0.125f; // hd^-0.5 = 64^-0.5
#pragma unroll
        for (int ci = 0; ci < 2; ++ci)
#pragma unroll
            for (int pr = 0; pr < 2; ++pr) {
                const int iie = pr * 2, iio = pr * 2 + 1;
                const int rho_e = ci * 64 + ty * 4 + iie;
                const int r384 = r0 + rho_e; // even
                const int u = r384 >> 1;
                const bool isH = (u < 96);
                const int cu = isH ? u : (u + 96);
                const int jA = isH ? (u >> 1) : ((u - 96) >> 1);
                const float invA = exp2f(-KC * (float)jA);
                const float invB = exp2f(-KC * (float)(jA + 48));
                const float be = bsel[cu];
                const float bo = bsel[cu + 96];
                float* orowE = osel + ((size_t)bb * CCH + cu) * NPIX + n0;
                float* orowO = osel + ((size_t)bb * CCH + cu + 96) * NPIX + n0;
#pragma unroll
                for (int cj = 0; cj < 2; ++cj) {
                    float4 oe, oo;
                    float* pe = &oe.x;
                    float* po = &oo.x;
#pragma unroll
                    for (int jj = 0; jj < 4; ++jj) {
                        int n = n0 + cj * 64 + tx * 4 + jj;
                        float p = (float)(isH ? (n >> 6) : (n & 63));
                        float sa, ca, sb, cb;
                        sincosf(p * invA, &sa, &ca);
                        sincosf(p * invB, &sb, &cb);
                        float te = acc[ci][cj][iie][jj] + be;
                        float to = acc[ci][cj][iio][jj] + bo;
                        float ve = te * ca - to * sa;
                        float vo = to * cb + te * sb;
                        if (which == 0) { ve = elu1(ve * qscale); vo = elu1(vo * qscale); }
                        else            { ve = elu1(ve);          vo = elu1(vo); }
                        pe[jj] = ve;
                        po[jj] = vo;
                    }
                    *(float4*)&orowE[cj * 64 + tx * 4] = oe;
                    *(float4*)&orowO[cj * 64 + tx * 4] = oo;
                }
            }
    }
}

// ---------------------------------------------------------------------------
// kv[bh][d][e] = sum_n k[b,64h+d,n] * v[b,64h+e,n];  ksum[bh][d] = sum_n k
// grid (48, 16): 16-way N split, fp32 atomics into zeroed workspace.
// ---------------------------------------------------------------------------
__global__ __launch_bounds__(256) void kv_kernel(
    const float* __restrict__ Kin, const float* __restrict__ Vin,
    float* __restrict__ KV, float* __restrict__ KS)
{
    __shared__ float Ks[32][68]; // [n][d]
    __shared__ float Vs[32][68];
    const int tid = threadIdx.x;
    const int bh = blockIdx.x;
    const int ns = blockIdx.y;
    const int b = bh / NHEADS, h = bh % NHEADS;
    const float* kb = Kin + ((size_t)b * CCH + h * 64) * NPIX;
    const float* vb = Vin + ((size_t)b * CCH + h * 64) * NPIX;
    const int drow = tid >> 2;
    const int nl = (tid & 3) * 8;
    const int td = (tid & 15) * 4;
    const int te = (tid >> 4) * 4;

    float acc[4][4];
    float ks[4] = {0.f, 0.f, 0.f, 0.f};
#pragma unroll
    for (int i = 0; i < 4; ++i)
#pragma unroll
        for (int j = 0; j < 4; ++j) acc[i][j] = 0.f;

    for (int n0 = ns * 256; n0 < ns * 256 + 256; n0 += 32) {
        __syncthreads();
        const float* kr = kb + (size_t)drow * NPIX + n0 + nl;
        const float* vr = vb + (size_t)drow * NPIX + n0 + nl;
        float4 k0 = *(const float4*)kr;
        float4 k1 = *(const float4*)(kr + 4);
        float4 v0 = *(const float4*)vr;
        float4 v1 = *(const float4*)(vr + 4);
        Ks[nl + 0][drow] = k0.x; Ks[nl + 1][drow] = k0.y;
        Ks[nl + 2][drow] = k0.z; Ks[nl + 3][drow] = k0.w;
        Ks[nl + 4][drow] = k1.x; Ks[nl + 5][drow] = k1.y;
        Ks[nl + 6][drow] = k1.z; Ks[nl + 7][drow] = k1.w;
        Vs[nl + 0][drow] = v0.x; Vs[nl + 1][drow] = v0.y;
        Vs[nl + 2][drow] = v0.z; Vs[nl + 3][drow] = v0.w;
        Vs[nl + 4][drow] = v1.x; Vs[nl + 5][drow] = v1.y;
        Vs[nl + 6][drow] = v1.z; Vs[nl + 7][drow] = v1.w;
        __syncthreads();
#pragma unroll 8
        for (int nn = 0; nn < 32; ++nn) {
            float4 a = *(const float4*)&Ks[nn][td];
            float4 w = *(const float4*)&Vs[nn][te];
            float av[4] = {a.x, a.y, a.z, a.w};
            float wv[4] = {w.x, w.y, w.z, w.w};
            ks[0] += av[0]; ks[1] += av[1]; ks[2] += av[2]; ks[3] += av[3];
#pragma unroll
            for (int i = 0; i < 4; ++i)
#pragma unroll
                for (int j = 0; j < 4; ++j) acc[i][j] += av[i] * wv[j];
        }
    }

    float* kvb = KV + (size_t)bh * 64 * 64;
#pragma unroll
    for (int i = 0; i < 4; ++i)
#pragma unroll
        for (int j = 0; j < 4; ++j)
            atomicAdd(&kvb[(td + i) * 64 + (te + j)], acc[i][j]);
    if (te == 0) {
#pragma unroll
        for (int i = 0; i < 4; ++i) atomicAdd(&KS[bh * 64 + td + i], ks[i]);
    }
}

// ---------------------------------------------------------------------------
// out[b,64h+e,n] = (sum_d q[b,64h+d,n]*kv[bh][d][e]) / (sum_d q*ksum + 1e-6)
// grid (32 n-tiles, 48 bh); kv + q-tile staged in LDS.
// ---------------------------------------------------------------------------
__global__ __launch_bounds__(256) void attn_kernel(
    const float* __restrict__ Q, const float* __restrict__ KV,
    const float* __restrict__ KS, float* __restrict__ O)
{
    __shared__ float Qs[64][132]; // [d][n]
    __shared__ float KVs[64][64]; // [d][e]
    __shared__ float KSs[64];
    const int tid = threadIdx.x;
    const int n0 = blockIdx.x * 128;
    const int bh = blockIdx.y;
    const int b = bh / NHEADS, h = bh % NHEADS;
    const float* qb = Q + ((size_t)b * CCH + h * 64) * NPIX;

    {
        const int row = tid >> 2;
        const int c0 = (tid & 3) * 32;
        const float* qr = qb + (size_t)row * NPIX + n0 + c0;
#pragma unroll
        for (int j = 0; j < 8; ++j)
            *(float4*)&Qs[row][c0 + j * 4] = *(const float4*)&qr[j * 4];
        const int kc = (tid & 3) * 16;
        const float* kvr = KV + (size_t)bh * 4096 + (size_t)row * 64 + kc;
#pragma unroll
        for (int j = 0; j < 4; ++j)
            *(float4*)&KVs[row][kc + j * 4] = *(const float4*)&kvr[j * 4];
        if (tid < 64) KSs[tid] = KS[bh * 64 + tid];
    }
    __syncthreads();

    const int tx = tid & 31;  // n: 4 cols at tx*4
    const int ty = tid >> 5;  // e: 8 rows at ty*8
    float acc[8][4];
    float accn[4] = {0.f, 0.f, 0.f, 0.f};
#pragma unroll
    for (int r = 0; r < 8; ++r)
#pragma unroll
        for (int j = 0; j < 4; ++j) acc[r][j] = 0.f;

#pragma unroll 8
    for (int d = 0; d < 64; ++d) {
        float4 qv = *(const float4*)&Qs[d][tx * 4];
        float qa[4] = {qv.x, qv.y, qv.z, qv.w};
        float ksv = KSs[d];
#pragma unroll
        for (int j = 0; j < 4; ++j) accn[j] += ksv * qa[j];
        float4 k0 = *(const float4*)&KVs[d][ty * 8];
        float4 k1 = *(const float4*)&KVs[d][ty * 8 + 4];
        float kva[8] = {k0.x, k0.y, k0.z, k0.w, k1.x, k1.y, k1.z, k1.w};
#pragma unroll
        for (int r = 0; r < 8; ++r)
#pragma unroll
            for (int j = 0; j < 4; ++j) acc[r][j] += kva[r] * qa[j];
    }

    float rcp[4];
#pragma unroll
    for (int j = 0; j < 4; ++j) rcp[j] = 1.f / (accn[j] + 1e-6f);
#pragma unroll
    for (int r = 0; r < 8; ++r) {
        float* orow = O + ((size_t)b * CCH + h * 64 + ty * 8 + r) * NPIX + n0 + tx * 4;
        float4 o4;
        o4.x = acc[r][0] * rcp[0];
        o4.y = acc[r][1] * rcp[1];
        o4.z = acc[r][2] * rcp[2];
        o4.w = acc[r][3] * rcp[3];
        *(float4*)orow = o4;
    }
}

__global__ void zero_kernel(float* p, int n)
{
    int i = blockIdx.x * blockDim.x + threadIdx.x;
    if (i < n) p[i] = 0.f;
}

extern "C" void kernel_launch(void* const* d_in, const int* in_sizes, int n_in,
                              void* d_out, int out_size, void* d_ws, size_t ws_size,
                              hipStream_t stream)
{
    const float* x   = (const float*)d_in[0];
    const float* Wq  = (const float*)d_in[1];
    const float* bq  = (const float*)d_in[2];
    const float* Wk  = (const float*)d_in[3];
    const float* bk  = (const float*)d_in[4];
    const float* Wv  = (const float*)d_in[5];
    const float* bv  = (const float*)d_in[6];
    const float* Wfc = (const float*)d_in[7];
    const float* bfc = (const float*)d_in[8];
    float* out = (float*)d_out;
    float* ws = (float*)d_ws;

    float* q    = ws;              // (B,C,N) post-rope, post-elu, scaled
    float* k    = ws + SZ;         // (B,C,N) post-rope, post-elu
    float* v    = ws + 2 * SZ;     // (B,C,N)
    float* kv   = ws + 3 * SZ;     // (48,64,64)
    float* ksum = kv + 48 * 64 * 64; // (48,64)
    float* o    = k;               // attention output reuses dead k buffer

    const int nz = 48 * 64 * 64 + 48 * 64;
    zero_kernel<<<(nz + 255) / 256, 256, 0, stream>>>(kv, nz);
    gemm_kernel<0><<<dim3(32, 9, BATCH), 256, 0, stream>>>(x, Wq, bq, Wk, bk, Wv, bv, q, k, v);
    kv_kernel<<<dim3(48, 16), 256, 0, stream>>>(k, v, kv, ksum);
    attn_kernel<<<dim3(32, 48), 256, 0, stream>>>(q, kv, ksum, o);
    gemm_kernel<1><<<dim3(32, 3, BATCH), 256, 0, stream>>>(o, Wfc, bfc, Wfc, bfc, Wfc, bfc, out, out, out);
}